// Round 12
// baseline (187.006 us; speedup 1.0000x reference)
//
#include <hip/hip_runtime.h>
#include <hip/hip_fp16.h>
#include <stdint.h>

#define N_NODES   4096
#define N_EDGES   128
#define D_X       128
#define PE_DIM    64
#define NUM_WALKS 10
#define N_WALKS_TOT (N_NODES * NUM_WALKS)   /* 40960 */
#define OUT_COLS  (D_X + PE_DIM)            /* 192 */
#define ROW_CAP   512u                      /* adjacency row stride (u16) */
#define VCAP      512u                      /* visitor list cap (max expected ~180) */
#define NBLK      512
#define NTHR      256
#define WPB       80                        /* walks per block: 512*80 = 40960 */

/* workspace layout (bytes) — ~13.2 MiB */
#define OFF_MASKS   0u                                    /* 64 KiB */
#define OFF_DEG     (OFF_MASKS + N_NODES * 16u)           /* 16 KiB */
#define OFF_ADJ     (OFF_DEG + N_NODES * 4u)              /* 4 MiB */
#define OFF_WM      (OFF_ADJ + N_NODES * ROW_CAP * 2u)    /* 5 MiB */
#define OFF_VCNT    (OFF_WM + (size_t)N_WALKS_TOT * PE_DIM * 2u) /* 16 KiB */
#define OFF_VLIST   (OFF_VCNT + N_NODES * 4u)             /* 4 MiB */

/* ---- monotonic grid barrier state (module .bss, zero at load).
   Each launch advances each counter by exactly NBLK, so "last arriver"
   (t % NBLK == 0) is base-independent -> deterministic across replays. ---- */
__device__ unsigned int g_ctr[3];
__device__ unsigned int g_flag[3];

__device__ __forceinline__ void gbar(int i) {
  __syncthreads();
  if (threadIdx.x == 0) {
    __threadfence();                                   /* publish (wb L2) */
    const unsigned int t = atomicAdd(&g_ctr[i], 1u) + 1u;
    const unsigned int target = ((t + NBLK - 1u) / NBLK) * NBLK;
    if (t == target) {
      atomicMax(&g_flag[i], target);                   /* release */
    } else {
      while (__hip_atomic_load(&g_flag[i], __ATOMIC_RELAXED,
                               __HIP_MEMORY_SCOPE_AGENT) < target)
        __builtin_amdgcn_s_sleep(1);
    }
    __threadfence();                                   /* acquire (inv L1/L2) */
  }
  __syncthreads();
}

/* ---- threefry2x32 (20 rounds) — cheap high-quality PRF ---- */
__device__ __forceinline__ void tf2x32(uint32_t kk0, uint32_t kk1,
                                       uint32_t x0, uint32_t x1,
                                       uint32_t& o0, uint32_t& o1) {
  const uint32_t kk2 = kk0 ^ kk1 ^ 0x1BD11BDAu;
  x0 += kk0; x1 += kk1;
  auto rnd = [&](int r) {
    x0 += x1;
    x1 = (x1 << r) | (x1 >> (32 - r));
    x1 ^= x0;
  };
  rnd(13); rnd(15); rnd(26); rnd(6);   x0 += kk1; x1 += kk2 + 1u;
  rnd(17); rnd(29); rnd(16); rnd(24);  x0 += kk2; x1 += kk0 + 2u;
  rnd(13); rnd(15); rnd(26); rnd(6);   x0 += kk0; x1 += kk1 + 3u;
  rnd(17); rnd(29); rnd(16); rnd(24);  x0 += kk1; x1 += kk2 + 4u;
  rnd(13); rnd(15); rnd(26); rnd(6);   x0 += kk2; x1 += kk0 + 5u;
  o0 = x0; o1 = x1;
}

/* ---- single fused kernel: 512 blocks x 256 threads, 64 KiB LDS (2/CU) ---- */
__global__ void __launch_bounds__(NTHR)
k_mega(const float* __restrict__ x, const float* __restrict__ inc,
       const float* __restrict__ embed, float* __restrict__ out,
       char* __restrict__ ws) {
  __shared__ ulonglong2 sm[N_NODES];                   /* 64 KiB */
  ulonglong2*     masks = (ulonglong2*)(ws + OFF_MASKS);
  unsigned int*   deg   = (unsigned int*)(ws + OFF_DEG);
  unsigned short* adj   = (unsigned short*)(ws + OFF_ADJ);
  __half*         wm    = (__half*)(ws + OFF_WM);
  unsigned int*   vcnt  = (unsigned int*)(ws + OFF_VCNT);
  unsigned short* vlist = (unsigned short*)(ws + OFF_VLIST);

  const int tid = threadIdx.x, wid = tid >> 6, lane = tid & 63;
  const int blk = blockIdx.x;

  /* ---- Phase A: incidence masks (8 nodes/block) + vcnt zeroing ---- */
  if (tid < 8) vcnt[blk * 8 + tid] = 0u;
#pragma unroll
  for (int r = 0; r < 2; ++r) {
    const int i = blk * 8 + wid * 2 + r;
    const float a = inc[i * N_EDGES + lane];
    const float b = inc[i * N_EDGES + 64 + lane];
    const unsigned long long m0 = __ballot(a != 0.f);
    const unsigned long long m1 = __ballot(b != 0.f);
    if (lane == 0) masks[i] = make_ulonglong2(m0, m1);
  }
  gbar(0);

  /* ---- Phase B: adjacency rows + degree (all masks staged in LDS) ---- */
  for (int k = tid; k < N_NODES; k += NTHR) sm[k] = masks[k];
  __syncthreads();
#pragma unroll
  for (int r = 0; r < 2; ++r) {
    const int i = blk * 8 + wid * 2 + r;
    const ulonglong2 mi = sm[i];
    unsigned short* row = adj + (unsigned int)i * ROW_CAP;
    unsigned int base = 0;
    for (int g = 0; g < N_NODES / 64; ++g) {
      const int j = g * 64 + lane;
      const ulonglong2 mj = sm[j];
      const bool pred = (((mi.x & mj.x) | (mi.y & mj.y)) != 0ull) && (j != i);
      const unsigned long long bal = __ballot(pred);
      if (pred) {
        const unsigned int off =
            (unsigned int)__popcll(bal & ((1ull << lane) - 1ull));
        const unsigned int pos = base + off;
        if (pos < ROW_CAP) row[pos] = (unsigned short)j;
      }
      base += (unsigned int)__popcll(bal);
    }
    if (lane == 0) deg[i] = (base < ROW_CAP) ? base : ROW_CAP;
  }
  gbar(1);

  /* ---- Phase C: per-thread walks (80/block) + means (4 waves x 20) ---- */
  uint4* srec = (uint4*)sm;                            /* reuse LDS */
  const uint32_t wbase = (uint32_t)blk * WPB;
  if (tid < WPB) {
    const uint32_t w = wbase + (uint32_t)tid;
    uint32_t r0, r1, r2, r3;
    tf2x32(0u, 42u, w, 0u, r0, r1);
    tf2x32(0u, 42u, w, 1u, r2, r3);
    const uint32_t n0 = w / NUM_WALKS;
    uint32_t n1, n2, n3, n4, nv;
    const unsigned int d0 = deg[n0];
    if (d0 == 0) {
      n1 = n2 = n3 = n4 = n0;
      nv = 1u;
    } else {
      uint32_t cur = n0;
      unsigned int d;
      cur = adj[(cur << 9) + (uint32_t)(((uint64_t)r0 * d0) >> 32)]; n1 = cur;
      d = deg[cur];
      cur = adj[(cur << 9) + (uint32_t)(((uint64_t)r1 * d) >> 32)]; n2 = cur;
      d = deg[cur];
      cur = adj[(cur << 9) + (uint32_t)(((uint64_t)r2 * d) >> 32)]; n3 = cur;
      d = deg[cur];
      cur = adj[(cur << 9) + (uint32_t)(((uint64_t)r3 * d) >> 32)]; n4 = cur;
      nv = 5u;
    }
    uint4 rec;
    rec.x = n0 | (n1 << 16);
    rec.y = n2 | (n3 << 16);
    rec.z = n4 | (nv << 16);
    rec.w = 0u;
    srec[tid] = rec;

    unsigned int s0 = atomicAdd(&vcnt[n0], 1u);
    if (s0 < VCAP) vlist[n0 * VCAP + s0] = (unsigned short)w;
    if (nv == 5u) {
      unsigned int s1 = atomicAdd(&vcnt[n1], 1u);
      if (s1 < VCAP) vlist[n1 * VCAP + s1] = (unsigned short)w;
      unsigned int s2 = atomicAdd(&vcnt[n2], 1u);
      if (s2 < VCAP) vlist[n2 * VCAP + s2] = (unsigned short)w;
      unsigned int s3 = atomicAdd(&vcnt[n3], 1u);
      if (s3 < VCAP) vlist[n3 * VCAP + s3] = (unsigned short)w;
      unsigned int s4 = atomicAdd(&vcnt[n4], 1u);
      if (s4 < VCAP) vlist[n4 * VCAP + s4] = (unsigned short)w;
    }
  }
  __syncthreads();
#pragma unroll 4
  for (int k = 0; k < WPB / 4; ++k) {
    const int widx = wid * (WPB / 4) + k;
    const uint4 rc = srec[widx];                       /* LDS broadcast */
    const uint32_t a0 = rc.x & 0xFFFFu, a1 = rc.x >> 16;
    const uint32_t a2 = rc.y & 0xFFFFu, a3 = rc.y >> 16;
    const uint32_t a4 = rc.z & 0xFFFFu, anv = rc.z >> 16;
    float s = embed[a0 * PE_DIM + lane];
    if (anv == 5u) {                                   /* wave-uniform branch */
      s += embed[a1 * PE_DIM + lane];
      s += embed[a2 * PE_DIM + lane];
      s += embed[a3 * PE_DIM + lane];
      s += embed[a4 * PE_DIM + lane];
    }
    wm[(size_t)(wbase + widx) * PE_DIM + lane] = __float2half(s / (float)anv);
  }
  gbar(2);

  /* ---- Phase D: gather visitor means (wave per node, 2 nodes/wave) ---- */
#pragma unroll
  for (int r = 0; r < 2; ++r) {
    const int v = blk * 8 + wid * 2 + r;
    const float2 xv = ((const float2*)(x + (size_t)v * D_X))[lane];
    ((float2*)(out + (size_t)v * OUT_COLS))[lane] = xv;

    unsigned int c = atomicAdd(&vcnt[v], 0u);          /* coherent read */
    if (c > VCAP) c = VCAP;
    const unsigned short* vl = vlist + (unsigned int)v * VCAP;
    float s = 0.f;
    for (unsigned int b2 = 0; b2 < c; b2 += 8) {
#pragma unroll
      for (int q = 0; q < 8; ++q) {
        const unsigned int idx = b2 + (unsigned int)q;
        const bool ok = idx < c;
        const unsigned int wwk = ok ? (unsigned int)vl[idx] : (unsigned int)vl[0];
        const float val = __half2float(wm[(size_t)wwk * PE_DIM + lane]);
        s += ok ? val : 0.f;
      }
    }
    out[(size_t)v * OUT_COLS + D_X + lane] = c ? s / (float)c : 0.f;
  }
}

extern "C" void kernel_launch(void* const* d_in, const int* in_sizes, int n_in,
                              void* d_out, int out_size, void* d_ws, size_t ws_size,
                              hipStream_t stream) {
  const float* x   = (const float*)d_in[0];
  const float* inc = (const float*)d_in[1];
  const float* emb = (const float*)d_in[2];
  float* out = (float*)d_out;
  char* ws = (char*)d_ws;

  void* args[] = {(void*)&x, (void*)&inc, (void*)&emb, (void*)&out, (void*)&ws};
  hipLaunchCooperativeKernel((const void*)k_mega, dim3(NBLK), dim3(NTHR),
                             args, 0, stream);
}

// Round 13
// 83.868 us; speedup vs baseline: 2.2298x; 2.2298x over previous
//
#include <hip/hip_runtime.h>
#include <hip/hip_fp16.h>
#include <stdint.h>

#define N_NODES   4096
#define N_EDGES   128
#define D_X       128
#define PE_DIM    64
#define NUM_WALKS 10
#define N_WALKS_TOT (N_NODES * NUM_WALKS)   /* 40960 */
#define OUT_COLS  (D_X + PE_DIM)            /* 192 */
#define VCAP      512u                      /* visitor list cap (max expected ~180) */
#define EMCAP     256                       /* edge member cap (max expected ~130) */
#define WPB       80                        /* walks per block in k_walkmean */

/* workspace layout (bytes) — ~9.1 MiB */
#define OFF_MASKS   0u                                          /* 64 KiB */
#define OFF_WM      (OFF_MASKS + N_NODES * 16u)                 /* 5 MiB */
#define OFF_VCNT    (OFF_WM + (size_t)N_WALKS_TOT * PE_DIM * 2u)/* 16 KiB */
#define OFF_VLIST   (OFF_VCNT + N_NODES * 4u)                   /* 4 MiB */

/* edge membership tables in module .bss: zero at load; k_gather re-zeroes
   g_ecnt for the NEXT launch => invariant ecnt==0 at every launch entry.
   (ws poison can't touch .bss; emem reads are bounded by this-launch ecnt.) */
__device__ unsigned int   g_ecnt[N_EDGES];
__device__ unsigned short g_emem[N_EDGES * EMCAP];

/* ---- threefry2x32 (20 rounds) — cheap high-quality PRF ---- */
__device__ __forceinline__ void tf2x32(uint32_t kk0, uint32_t kk1,
                                       uint32_t x0, uint32_t x1,
                                       uint32_t& o0, uint32_t& o1) {
  const uint32_t kk2 = kk0 ^ kk1 ^ 0x1BD11BDAu;
  x0 += kk0; x1 += kk1;
  auto rnd = [&](int r) {
    x0 += x1;
    x1 = (x1 << r) | (x1 >> (32 - r));
    x1 ^= x0;
  };
  rnd(13); rnd(15); rnd(26); rnd(6);   x0 += kk1; x1 += kk2 + 1u;
  rnd(17); rnd(29); rnd(16); rnd(24);  x0 += kk2; x1 += kk0 + 2u;
  rnd(13); rnd(15); rnd(26); rnd(6);   x0 += kk0; x1 += kk1 + 3u;
  rnd(17); rnd(29); rnd(16); rnd(24);  x0 += kk1; x1 += kk2 + 4u;
  rnd(13); rnd(15); rnd(26); rnd(6);   x0 += kk2; x1 += kk0 + 5u;
  o0 = x0; o1 = x1;
}

/* ---- K1: node masks + edge member lists + vcnt zero (one wave/node) ---- */
__global__ void k_build(const float* __restrict__ inc,
                        ulonglong2* __restrict__ masks,
                        unsigned int* __restrict__ vcnt) {
  const int wid = threadIdx.x >> 6, lane = threadIdx.x & 63;
  const int i = blockIdx.x * 4 + wid;
  const float a = inc[i * N_EDGES + lane];        /* edge  lane      */
  const float b = inc[i * N_EDGES + 64 + lane];   /* edge  64+lane   */
  const unsigned long long m0 = __ballot(a != 0.f);
  const unsigned long long m1 = __ballot(b != 0.f);
  if (lane == 0) {
    masks[i] = make_ulonglong2(m0, m1);
    vcnt[i] = 0u;
  }
  if (a != 0.f) {
    const unsigned int s = atomicAdd(&g_ecnt[lane], 1u);
    if (s < EMCAP) g_emem[(lane << 8) + s] = (unsigned short)i;
  }
  if (b != 0.f) {
    const unsigned int s = atomicAdd(&g_ecnt[64 + lane], 1u);
    if (s < EMCAP) g_emem[((64 + lane) << 8) + s] = (unsigned short)i;
  }
}

/* ---- K2: per-thread walks via rejection sampling (uniform over distinct
   neighbors, no adjacency matrix) + per-wave means (lane == dim). ---- */
__global__ void __launch_bounds__(256)
k_walkmean(const ulonglong2* __restrict__ masks,
           const float* __restrict__ embed,
           __half* __restrict__ wm,
           unsigned int* __restrict__ vcnt, unsigned short* __restrict__ vlist) {
  __shared__ uint4 srec[WPB];
  __shared__ unsigned int secnt[N_EDGES];
  const int tid = threadIdx.x, wid = tid >> 6, lane = tid & 63;
  const uint32_t wbase = (uint32_t)blockIdx.x * WPB;

  if (tid < N_EDGES) secnt[tid] = g_ecnt[tid];
  __syncthreads();

  if (tid < WPB) {
    const uint32_t w = wbase + (uint32_t)tid;
    const uint32_t n0 = w / NUM_WALKS;
    ulonglong2 cmk = masks[n0];

    /* alive iff some edge of n0 has >=2 members */
    bool alive = false;
    {
      unsigned long long lo = cmk.x, hi = cmk.y;
      while (lo) { const int e = __ffsll(lo) - 1; lo &= lo - 1;
                   alive |= secnt[e] >= 2u; }
      while (hi) { const int e = __ffsll(hi) - 1; hi &= hi - 1;
                   alive |= secnt[64 + e] >= 2u; }
    }

    uint32_t nn[5];
    nn[0] = n0;
    uint32_t nv = 1u;
    if (!alive) {
      nn[1] = nn[2] = nn[3] = nn[4] = n0;
    } else {
      uint32_t cur = n0;
      nv = 5u;
#pragma unroll
      for (int step = 0; step < 4; ++step) {
        /* total multiset weight W of cur's edges */
        uint32_t W = 0;
        {
          unsigned long long lo = cmk.x, hi = cmk.y;
          while (lo) { const int e = __ffsll(lo) - 1; lo &= lo - 1;
                       W += secnt[e]; }
          while (hi) { const int e = __ffsll(hi) - 1; hi &= hi - 1;
                       W += secnt[64 + e]; }
        }
        uint32_t nxt = cur;
        ulonglong2 nmk = cmk;
#pragma unroll 1
        for (int t = 0; t < 16; ++t) {
          uint32_t r0, r1;
          tf2x32(0u, 42u, w, 2u + ((uint32_t)step << 4) + (uint32_t)t, r0, r1);
          uint32_t rem = (uint32_t)(((uint64_t)r0 * W) >> 32);  /* [0,W) */
          /* locate edge + member index by cumulative scan */
          int edge = -1;
          {
            unsigned long long lo = cmk.x;
            while (lo) { const int e = __ffsll(lo) - 1; lo &= lo - 1;
                         const uint32_t c = secnt[e];
                         if (rem < c) { edge = e; break; }
                         rem -= c; }
            if (edge < 0) {
              unsigned long long hi = cmk.y;
              while (hi) { const int e = __ffsll(hi) - 1; hi &= hi - 1;
                           const uint32_t c = secnt[64 + e];
                           if (rem < c) { edge = 64 + e; break; }
                           rem -= c; }
            }
          }
          if (rem >= (uint32_t)EMCAP) continue;       /* overflow guard */
          const uint32_t cand = g_emem[(edge << 8) + rem];
          if (cand == cur) continue;                  /* self-loop excluded */
          const ulonglong2 km = masks[cand];
          const uint32_t k = (uint32_t)(__popcll(km.x & cmk.x) +
                                        __popcll(km.y & cmk.y));
          /* accept with prob ~1/k -> uniform over distinct neighbors */
          if (k == 1u || (uint32_t)(((uint64_t)r1 * k) >> 32) == 0u) {
            nxt = cand; nmk = km; break;
          }
        }
        cur = nxt; cmk = nmk;
        nn[step + 1] = cur;
      }
    }

    uint4 rec;
    rec.x = nn[0] | (nn[1] << 16);
    rec.y = nn[2] | (nn[3] << 16);
    rec.z = nn[4] | (nv << 16);
    rec.w = 0u;
    srec[tid] = rec;

    /* visit records */
    unsigned int s0 = atomicAdd(&vcnt[nn[0]], 1u);
    if (s0 < VCAP) vlist[nn[0] * VCAP + s0] = (unsigned short)w;
    if (nv == 5u) {
      unsigned int s1 = atomicAdd(&vcnt[nn[1]], 1u);
      if (s1 < VCAP) vlist[nn[1] * VCAP + s1] = (unsigned short)w;
      unsigned int s2 = atomicAdd(&vcnt[nn[2]], 1u);
      if (s2 < VCAP) vlist[nn[2] * VCAP + s2] = (unsigned short)w;
      unsigned int s3 = atomicAdd(&vcnt[nn[3]], 1u);
      if (s3 < VCAP) vlist[nn[3] * VCAP + s3] = (unsigned short)w;
      unsigned int s4 = atomicAdd(&vcnt[nn[4]], 1u);
      if (s4 < VCAP) vlist[nn[4] * VCAP + s4] = (unsigned short)w;
    }
  }
  __syncthreads();

  /* means — wave wid handles walks [wid*20, wid*20+20) */
#pragma unroll 4
  for (int k = 0; k < WPB / 4; ++k) {
    const int widx = wid * (WPB / 4) + k;
    const uint4 rc = srec[widx];                 /* LDS broadcast */
    const uint32_t a0 = rc.x & 0xFFFFu, a1 = rc.x >> 16;
    const uint32_t a2 = rc.y & 0xFFFFu, a3 = rc.y >> 16;
    const uint32_t a4 = rc.z & 0xFFFFu, anv = rc.z >> 16;
    float s = embed[a0 * PE_DIM + lane];
    if (anv == 5u) {                             /* wave-uniform branch */
      s += embed[a1 * PE_DIM + lane];
      s += embed[a2 * PE_DIM + lane];
      s += embed[a3 * PE_DIM + lane];
      s += embed[a4 * PE_DIM + lane];
    }
    wm[(size_t)(wbase + widx) * PE_DIM + lane] = __float2half(s / (float)anv);
  }
}

/* ---- K3: block per node; 4 waves x 8-deep ILP gather of visitor means;
   also re-zeroes g_ecnt for the next launch (no consumer this launch). ---- */
__global__ void __launch_bounds__(256)
k_gather(const __half* __restrict__ walk_m,
         const unsigned int* __restrict__ vcnt,
         const unsigned short* __restrict__ vlist,
         const float* __restrict__ x,
         float* __restrict__ out) {
  __shared__ float red[4][PE_DIM];
  const int wid = threadIdx.x >> 6, lane = threadIdx.x & 63;
  const int v = blockIdx.x;

  if (v == 0 && threadIdx.x < N_EDGES) g_ecnt[threadIdx.x] = 0u;

  /* x passthrough by wave 3 (independent of the reduction) */
  if (wid == 3) {
    const float2 xv = ((const float2*)(x + (size_t)v * D_X))[lane];
    ((float2*)(out + (size_t)v * OUT_COLS))[lane] = xv;
  }

  unsigned int c = vcnt[v];
  if (c > VCAP) c = VCAP;
  const unsigned short* vl = vlist + (unsigned int)v * VCAP;

  float s = 0.f;
  for (unsigned int base = (unsigned int)wid * 8u; base < c; base += 32u) {
#pragma unroll
    for (int q = 0; q < 8; ++q) {
      const unsigned int idx = base + (unsigned int)q;
      const bool ok = idx < c;
      const unsigned int ww = ok ? (unsigned int)vl[idx] : (unsigned int)vl[0];
      const float val = __half2float(walk_m[(size_t)ww * PE_DIM + lane]);
      s += ok ? val : 0.f;
    }
  }
  red[wid][lane] = s;
  __syncthreads();
  if (wid == 0) {
    const float t = red[0][lane] + red[1][lane] + red[2][lane] + red[3][lane];
    out[(size_t)v * OUT_COLS + D_X + lane] = c ? t / (float)c : 0.f;
  }
}

extern "C" void kernel_launch(void* const* d_in, const int* in_sizes, int n_in,
                              void* d_out, int out_size, void* d_ws, size_t ws_size,
                              hipStream_t stream) {
  const float* x   = (const float*)d_in[0];
  const float* inc = (const float*)d_in[1];
  const float* emb = (const float*)d_in[2];
  float* out = (float*)d_out;

  char* ws = (char*)d_ws;
  ulonglong2*     masks = (ulonglong2*)(ws + OFF_MASKS);
  __half*         wm    = (__half*)(ws + OFF_WM);
  unsigned int*   vcnt  = (unsigned int*)(ws + OFF_VCNT);
  unsigned short* vlist = (unsigned short*)(ws + OFF_VLIST);

  k_build   <<<N_NODES / 4, 256, 0, stream>>>(inc, masks, vcnt);
  k_walkmean<<<N_WALKS_TOT / WPB, 256, 0, stream>>>(masks, emb, wm, vcnt,
                                                    vlist);
  k_gather  <<<N_NODES, 256, 0, stream>>>(wm, vcnt, vlist, x, out);
}

// Round 14
// 82.853 us; speedup vs baseline: 2.2571x; 1.0123x over previous
//
#include <hip/hip_runtime.h>
#include <hip/hip_fp16.h>
#include <stdint.h>

#define N_NODES   4096
#define N_EDGES   128
#define D_X       128
#define PE_DIM    64
#define NUM_WALKS 10
#define N_WALKS_TOT (N_NODES * NUM_WALKS)   /* 40960 */
#define OUT_COLS  (D_X + PE_DIM)            /* 192 */
#define VCAP      512u                      /* visitor list cap (max expected ~180) */
#define EMCAP     256                       /* edge member cap (max expected ~130) */

/* workspace layout (bytes) — ~9.1 MiB */
#define OFF_MASKS   0u                                          /* 64 KiB */
#define OFF_WM      (OFF_MASKS + N_NODES * 16u)                 /* 5 MiB */
#define OFF_VCNT    (OFF_WM + (size_t)N_WALKS_TOT * PE_DIM * 2u)/* 16 KiB */
#define OFF_VLIST   (OFF_VCNT + N_NODES * 4u)                   /* 4 MiB */

/* edge membership tables in module .bss: zero at load; k_gather re-zeroes
   g_ecnt for the NEXT launch => invariant ecnt==0 at every launch entry. */
__device__ unsigned int   g_ecnt[N_EDGES];
__device__ unsigned short g_emem[N_EDGES * EMCAP];

/* ---- threefry2x32 (20 rounds) — cheap high-quality PRF ---- */
__device__ __forceinline__ void tf2x32(uint32_t kk0, uint32_t kk1,
                                       uint32_t x0, uint32_t x1,
                                       uint32_t& o0, uint32_t& o1) {
  const uint32_t kk2 = kk0 ^ kk1 ^ 0x1BD11BDAu;
  x0 += kk0; x1 += kk1;
  auto rnd = [&](int r) {
    x0 += x1;
    x1 = (x1 << r) | (x1 >> (32 - r));
    x1 ^= x0;
  };
  rnd(13); rnd(15); rnd(26); rnd(6);   x0 += kk1; x1 += kk2 + 1u;
  rnd(17); rnd(29); rnd(16); rnd(24);  x0 += kk2; x1 += kk0 + 2u;
  rnd(13); rnd(15); rnd(26); rnd(6);   x0 += kk0; x1 += kk1 + 3u;
  rnd(17); rnd(29); rnd(16); rnd(24);  x0 += kk1; x1 += kk2 + 4u;
  rnd(13); rnd(15); rnd(26); rnd(6);   x0 += kk2; x1 += kk0 + 5u;
  o0 = x0; o1 = x1;
}

/* ---- K1: node masks + edge member lists + vcnt zero (one wave/node) ---- */
__global__ void k_build(const float* __restrict__ inc,
                        ulonglong2* __restrict__ masks,
                        unsigned int* __restrict__ vcnt) {
  const int wid = threadIdx.x >> 6, lane = threadIdx.x & 63;
  const int i = blockIdx.x * 4 + wid;
  const float a = inc[i * N_EDGES + lane];        /* edge lane    */
  const float b = inc[i * N_EDGES + 64 + lane];   /* edge 64+lane */
  const unsigned long long m0 = __ballot(a != 0.f);
  const unsigned long long m1 = __ballot(b != 0.f);
  if (lane == 0) {
    masks[i] = make_ulonglong2(m0, m1);
    vcnt[i] = 0u;
  }
  if (a != 0.f) {
    const unsigned int s = atomicAdd(&g_ecnt[lane], 1u);
    if (s < EMCAP) g_emem[(lane << 8) + s] = (unsigned short)i;
  }
  if (b != 0.f) {
    const unsigned int s = atomicAdd(&g_ecnt[64 + lane], 1u);
    if (s < EMCAP) g_emem[((64 + lane) << 8) + s] = (unsigned short)i;
  }
}

/* ---- K2: walks via WAVE-PARALLEL rejection sampling: 16 lanes per walk
   propose independently; group-ballot picks first acceptor (uniform over
   distinct neighbors). 4 walks/wave; group-uniform control flow. ---- */
__global__ void __launch_bounds__(256)
k_walkmean(const ulonglong2* __restrict__ masks,
           const float* __restrict__ embed,
           __half* __restrict__ wm,
           unsigned int* __restrict__ vcnt, unsigned short* __restrict__ vlist) {
  __shared__ unsigned int secnt[N_EDGES];
  const int tid = threadIdx.x, wid = tid >> 6, lane = tid & 63;
  if (tid < N_EDGES) secnt[tid] = g_ecnt[tid];
  __syncthreads();

  const int grp = lane >> 4;                    /* walk group 0..3 in wave */
  const int gl  = lane & 15;                    /* lane in group */
  const uint32_t w =
      ((uint32_t)blockIdx.x * 4u + (uint32_t)wid) * 4u + (uint32_t)grp;
  const uint32_t n0 = w / NUM_WALKS;

  ulonglong2 cmk = masks[n0];                   /* group-uniform */

  /* alive iff some edge of n0 has >=2 members */
  bool alive = false;
  { unsigned long long lo = cmk.x;
    while (lo) { const int e = __ffsll(lo) - 1; lo &= lo - 1;
                 alive |= (secnt[e] >= 2u); } }
  { unsigned long long hi = cmk.y;
    while (hi) { const int e = __ffsll(hi) - 1; hi &= hi - 1;
                 alive |= (secnt[64 + e] >= 2u); } }

  uint32_t nn0 = n0, nn1 = n0, nn2 = n0, nn3 = n0, nn4 = n0;
  uint32_t nv = 1u;
  if (alive) {
    nv = 5u;
    uint32_t cur = n0;
#pragma unroll
    for (int step = 0; step < 4; ++step) {
      /* total multiset weight of cur's edges (group-uniform scan) */
      uint32_t W = 0;
      { unsigned long long lo = cmk.x;
        while (lo) { const int e = __ffsll(lo) - 1; lo &= lo - 1;
                     W += secnt[e]; } }
      { unsigned long long hi = cmk.y;
        while (hi) { const int e = __ffsll(hi) - 1; hi &= hi - 1;
                     W += secnt[64 + e]; } }

      /* per-lane independent proposal */
      uint32_t r0, r1;
      tf2x32(0u, 42u, w, 2u + (uint32_t)(step * 16) + (uint32_t)gl, r0, r1);
      uint32_t rem = (uint32_t)(((uint64_t)r0 * W) >> 32);  /* [0,W) */
      int edge = -1; uint32_t slot = 0u;
      { unsigned long long lo = cmk.x;
        while (lo) { const int e = __ffsll(lo) - 1; lo &= lo - 1;
                     const uint32_t c = secnt[e];
                     if (edge < 0) { if (rem < c) { edge = e; slot = rem; }
                                     else rem -= c; } } }
      { unsigned long long hi = cmk.y;
        while (hi) { const int e = __ffsll(hi) - 1; hi &= hi - 1;
                     const uint32_t c = secnt[64 + e];
                     if (edge < 0) { if (rem < c) { edge = 64 + e; slot = rem; }
                                     else rem -= c; } } }
      bool acc = false; uint32_t cand = 0u;
      if (edge >= 0 && slot < (uint32_t)EMCAP) {
        cand = g_emem[((unsigned int)edge << 8) + slot];
        if (cand != cur) {
          const ulonglong2 km = masks[cand];
          const uint32_t k = (uint32_t)(__popcll(km.x & cmk.x) +
                                        __popcll(km.y & cmk.y));
          /* accept w.p. ~1/k -> uniform over distinct neighbors */
          acc = (k <= 1u) ||
                ((uint32_t)(((uint64_t)r1 * (uint64_t)k) >> 32) == 0u);
        }
      }
      const unsigned int gm =
          (unsigned int)(__ballot(acc) >> (grp * 16)) & 0xFFFFu;
      if (gm) {                                 /* group-uniform branch */
        const int src = grp * 16 + (__ffs(gm) - 1);
        cur = __shfl(cand, src);
        cmk = masks[cur];                       /* group-uniform reload */
      }                                         /* else: keep cur (p~1e-11) */
      if (step == 0) nn1 = cur; else if (step == 1) nn2 = cur;
      else if (step == 2) nn3 = cur; else nn4 = cur;
    }
  }

  /* means + visit records: iterate the wave's 4 walks (lane == dim) */
#pragma unroll
  for (int q = 0; q < 4; ++q) {
    const int base = q * 16;
    const uint32_t b0 = __shfl(nn0, base);
    const uint32_t b1 = __shfl(nn1, base);
    const uint32_t b2 = __shfl(nn2, base);
    const uint32_t b3 = __shfl(nn3, base);
    const uint32_t b4 = __shfl(nn4, base);
    const uint32_t bv = __shfl(nv,  base);
    const uint32_t bw = __shfl(w,   base);
    float s = embed[b0 * PE_DIM + lane];
    if (bv == 5u) {                             /* wave-uniform branch */
      s += embed[b1 * PE_DIM + lane];
      s += embed[b2 * PE_DIM + lane];
      s += embed[b3 * PE_DIM + lane];
      s += embed[b4 * PE_DIM + lane];
    }
    wm[(size_t)bw * PE_DIM + lane] = __float2half(s / (float)bv);
    if ((uint32_t)lane < bv) {
      uint32_t node = b0;
      if (lane == 1) node = b1;
      if (lane == 2) node = b2;
      if (lane == 3) node = b3;
      if (lane == 4) node = b4;
      const unsigned int sl = atomicAdd(&vcnt[node], 1u);
      if (sl < VCAP) vlist[node * VCAP + sl] = (unsigned short)bw;
    }
  }
}

/* ---- K3: block per node; 4 waves x 8-deep ILP gather of visitor means;
   re-zeroes g_ecnt for the next launch; x passthrough on wave 3. ---- */
__global__ void __launch_bounds__(256)
k_gather(const __half* __restrict__ walk_m,
         const unsigned int* __restrict__ vcnt,
         const unsigned short* __restrict__ vlist,
         const float* __restrict__ x,
         float* __restrict__ out) {
  __shared__ float red[4][PE_DIM];
  const int wid = threadIdx.x >> 6, lane = threadIdx.x & 63;
  const int v = blockIdx.x;

  if (v == 0 && threadIdx.x < N_EDGES) g_ecnt[threadIdx.x] = 0u;

  if (wid == 3) {
    const float2 xv = ((const float2*)(x + (size_t)v * D_X))[lane];
    ((float2*)(out + (size_t)v * OUT_COLS))[lane] = xv;
  }

  unsigned int c = vcnt[v];
  if (c > VCAP) c = VCAP;
  const unsigned short* vl = vlist + (unsigned int)v * VCAP;

  float s = 0.f;
  for (unsigned int base = (unsigned int)wid * 8u; base < c; base += 32u) {
#pragma unroll
    for (int q = 0; q < 8; ++q) {
      const unsigned int idx = base + (unsigned int)q;
      const bool ok = idx < c;
      const unsigned int ww = ok ? (unsigned int)vl[idx] : (unsigned int)vl[0];
      const float val = __half2float(walk_m[(size_t)ww * PE_DIM + lane]);
      s += ok ? val : 0.f;
    }
  }
  red[wid][lane] = s;
  __syncthreads();
  if (wid == 0) {
    const float t = red[0][lane] + red[1][lane] + red[2][lane] + red[3][lane];
    out[(size_t)v * OUT_COLS + D_X + lane] = c ? t / (float)c : 0.f;
  }
}

extern "C" void kernel_launch(void* const* d_in, const int* in_sizes, int n_in,
                              void* d_out, int out_size, void* d_ws, size_t ws_size,
                              hipStream_t stream) {
  const float* x   = (const float*)d_in[0];
  const float* inc = (const float*)d_in[1];
  const float* emb = (const float*)d_in[2];
  float* out = (float*)d_out;

  char* ws = (char*)d_ws;
  ulonglong2*     masks = (ulonglong2*)(ws + OFF_MASKS);
  __half*         wm    = (__half*)(ws + OFF_WM);
  unsigned int*   vcnt  = (unsigned int*)(ws + OFF_VCNT);
  unsigned short* vlist = (unsigned short*)(ws + OFF_VLIST);

  k_build   <<<N_NODES / 4, 256, 0, stream>>>(inc, masks, vcnt);
  k_walkmean<<<N_WALKS_TOT / 16, 256, 0, stream>>>(masks, emb, wm, vcnt,
                                                   vlist);
  k_gather  <<<N_NODES, 256, 0, stream>>>(wm, vcnt, vlist, x, out);
}